// Round 2
// baseline (1294.945 us; speedup 1.0000x reference)
//
#include <hip/hip_runtime.h>
#include <hip/hip_bf16.h>

#define EPSN 1e-12f

// Problem dims (fixed by setup_inputs)
#define BB   8
#define NN   1024
#define DIN  384
#define DOUT 384
#define SS   128
#define PP   128

// Main-kernel tiling
#define NBLK 64   // tokens per block (one per lane)
#define DBLK 4    // d per block (one per wave)
#define CCH  16   // c chunk staged in LDS

// ---------------------------------------------------------------------------
// Kernel 1: wn[s][p] = scale * maps_weight[s][p] / max(||maps_weight[s]||, eps)
// ---------------------------------------------------------------------------
__global__ void wnorm_kernel(const float* __restrict__ mw,
                             const float* __restrict__ scale,
                             float* __restrict__ wn) {
    __shared__ float row[PP];
    const int s = blockIdx.x;
    const int t = threadIdx.x;
    row[t] = mw[s * PP + t];
    __syncthreads();
    float ss = 0.f;
#pragma unroll
    for (int p = 0; p < PP; ++p) ss = fmaf(row[p], row[p], ss);
    const float nrm = fmaxf(sqrtf(ss), EPSN);
    wn[s * PP + t] = scale[0] * row[t] / nrm;
}

// ---------------------------------------------------------------------------
// Kernel 2: coef[n][s] = softmax_s( dot(l2norm(pe[n]), wn[s]) )
// one block per token n, 128 threads (thread = slot s)
// ---------------------------------------------------------------------------
__global__ void coef_kernel(const float* __restrict__ pe,
                            const float* __restrict__ wn,
                            float* __restrict__ coef) {
    __shared__ float pen[PP];
    __shared__ float red[SS];
    const int n = blockIdx.x;
    const int t = threadIdx.x;
    pen[t] = pe[n * PP + t];
    __syncthreads();
    float ss = 0.f;
#pragma unroll
    for (int p = 0; p < PP; ++p) ss = fmaf(pen[p], pen[p], ss);
    const float rn = 1.0f / fmaxf(sqrtf(ss), EPSN);

    const float* wrow = wn + t * PP;
    float lg = 0.f;
#pragma unroll
    for (int p = 0; p < PP; ++p) lg = fmaf(pen[p], wrow[p], lg);
    lg *= rn;

    // softmax across the 128 threads
    red[t] = lg;
    __syncthreads();
    for (int off = 64; off > 0; off >>= 1) {
        if (t < off) red[t] = fmaxf(red[t], red[t + off]);
        __syncthreads();
    }
    const float m = red[0];
    __syncthreads();
    const float e = expf(lg - m);
    red[t] = e;
    __syncthreads();
    for (int off = 64; off > 0; off >>= 1) {
        if (t < off) red[t] += red[t + off];
        __syncthreads();
    }
    coef[n * SS + t] = e / red[0];
}

// ---------------------------------------------------------------------------
// Kernel 3 (main, fused combine+apply):
//   out[b,n,d] = sum_c x[b,n,c] * (sum_s coef[n,s]*weight[d,c,s]) + sum_s coef[n,s]*bias[d,s]
// Block: 256 threads = 4 waves. lane = token (64 tokens), wave = one d.
// coef row register-resident; weight rows wave-uniform -> scalar (s_load) path;
// x double-buffered global->reg->LDS (T14 async-stage split).
// ---------------------------------------------------------------------------
__global__ __launch_bounds__(256, 2) void topo_main_kernel(
    const float* __restrict__ x,
    const float* __restrict__ weight,
    const float* __restrict__ bias,
    const float* __restrict__ coef,
    float* __restrict__ out) {
    __shared__ float4 xld[BB][CCH / 4][NBLK];   // 32 KiB

    const int tid  = threadIdx.x;
    const int lane = tid & 63;
    const int wid  = tid >> 6;
    const int dgrp = blockIdx.x;   // fastest dim: consecutive blocks share the x slice
    const int ngrp = blockIdx.y;
    const int n    = ngrp * NBLK + lane;
    const int d    = __builtin_amdgcn_readfirstlane(dgrp * DBLK + wid);

    // per-thread staging assignment (fixed): ccg = tid&3, ni = (tid>>2)&63, b = k
    const int sccg = tid & 3;
    const int sni  = (tid >> 2) & 63;
    const float* xstage_base = x + ((size_t)ngrp * NBLK + sni) * DIN + sccg * 4;

    // coef row for this lane's token -> registers (128 VGPRs)
    float cf[SS];
    {
        const float4* crow = reinterpret_cast<const float4*>(coef + n * SS);
#pragma unroll
        for (int q = 0; q < SS / 4; ++q) {
            const float4 c4 = crow[q];
            cf[4 * q + 0] = c4.x;
            cf[4 * q + 1] = c4.y;
            cf[4 * q + 2] = c4.z;
            cf[4 * q + 3] = c4.w;
        }
    }

    float acc[BB];
#pragma unroll
    for (int b = 0; b < BB; ++b) acc[b] = 0.f;

    const float* wbase = weight + (size_t)d * (DIN * SS);

    // --- prologue: load chunk 0 into registers ---
    float4 xreg[BB];
#pragma unroll
    for (int b = 0; b < BB; ++b)
        xreg[b] = *reinterpret_cast<const float4*>(xstage_base + (size_t)b * NN * DIN);

    for (int c0 = 0; c0 < DIN; c0 += CCH) {
        __syncthreads();   // previous chunk's readers done
#pragma unroll
        for (int b = 0; b < BB; ++b) xld[b][sccg][sni] = xreg[b];
        __syncthreads();

        // prefetch next chunk into registers; latency hides under compute below
        if (c0 + CCH < DIN) {
#pragma unroll
            for (int b = 0; b < BB; ++b)
                xreg[b] = *reinterpret_cast<const float4*>(
                    xstage_base + (size_t)b * NN * DIN + (c0 + CCH));
        }

        for (int ccg = 0; ccg < CCH / 4; ++ccg) {
            // 4 independent dot chains over s (ILP); wr0 is wave-uniform -> s_load
            const float* wr0 = wbase + (size_t)(c0 + ccg * 4) * SS;
            float wv0 = 0.f, wv1 = 0.f, wv2 = 0.f, wv3 = 0.f;
#pragma unroll
            for (int s = 0; s < SS; ++s) {
                const float cs = cf[s];
                wv0 = fmaf(cs, wr0[s + 0 * SS], wv0);
                wv1 = fmaf(cs, wr0[s + 1 * SS], wv1);
                wv2 = fmaf(cs, wr0[s + 2 * SS], wv2);
                wv3 = fmaf(cs, wr0[s + 3 * SS], wv3);
            }
#pragma unroll
            for (int b = 0; b < BB; ++b) {
                const float4 xv = xld[b][ccg][lane];
                acc[b] = fmaf(xv.x, wv0, acc[b]);
                acc[b] = fmaf(xv.y, wv1, acc[b]);
                acc[b] = fmaf(xv.z, wv2, acc[b]);
                acc[b] = fmaf(xv.w, wv3, acc[b]);
            }
        }
    }

    // bias epilogue: bvec[n,d] = dot(coef[n], bias[d]) — bias row wave-uniform
    const float* brow = bias + (size_t)d * SS;
    float bd = 0.f;
#pragma unroll
    for (int s = 0; s < SS; ++s) bd = fmaf(cf[s], brow[s], bd);

#pragma unroll
    for (int b = 0; b < BB; ++b)
        out[((size_t)b * NN + n) * DOUT + d] = acc[b] + bd;
}

// ---------------------------------------------------------------------------
extern "C" void kernel_launch(void* const* d_in, const int* in_sizes, int n_in,
                              void* d_out, int out_size, void* d_ws, size_t ws_size,
                              hipStream_t stream) {
    const float* x     = (const float*)d_in[0];   // (8,1024,384)
    const float* pe    = (const float*)d_in[1];   // (1024,128)
    const float* mw    = (const float*)d_in[2];   // (128,128)
    const float* scale = (const float*)d_in[3];   // ()
    const float* wgt   = (const float*)d_in[4];   // (384,384,128)
    const float* bias  = (const float*)d_in[5];   // (384,128)
    float* out = (float*)d_out;

    float* wn   = (float*)d_ws;                        // 128*128 floats = 64 KiB
    float* coef = wn + SS * PP;                        // 1024*128 floats = 512 KiB

    wnorm_kernel<<<dim3(SS), dim3(PP), 0, stream>>>(mw, scale, wn);
    coef_kernel<<<dim3(NN), dim3(PP), 0, stream>>>(pe, wn, coef);
    topo_main_kernel<<<dim3(DOUT / DBLK, NN / NBLK), dim3(256), 0, stream>>>(
        x, wgt, bias, coef, out);
}